// Round 10
// baseline (336.043 us; speedup 1.0000x reference)
//
#include <hip/hip_runtime.h>
#include <hip/hip_bf16.h>
#include <stdint.h>

// Problem constants
#define M_DIM 8192   // B*S = 4*2048
#define N_C   4096   // contraction dim (N in reference)
#define K_OUT 4096   // output features (K in reference)
#define NGRP  32
#define NT    (N_C / 32)   // 128 K-tiles of 32

typedef __attribute__((ext_vector_type(8))) short bf16x8;
typedef __attribute__((ext_vector_type(4))) float f32x4;

// fp32 -> bf16, round-to-nearest-even (inputs are finite)
__device__ __forceinline__ unsigned short f2b(float f) {
  unsigned u = __float_as_uint(f);
  return (unsigned short)((u + 0x7fffu + ((u >> 16) & 1u)) >> 16);
}

__device__ __forceinline__ void gload_lds16(const void* g, void* l) {
  __builtin_amdgcn_global_load_lds(
      (const __attribute__((address_space(1))) void*)g,
      (__attribute__((address_space(3))) void*)l,
      16, 0, 0);
}

// ---- x fp32 -> bf16 ----
__global__ void convert_x_kernel(const float* __restrict__ x,
                                 unsigned short* __restrict__ xb) {
  const int total = (M_DIM * N_C) / 8;
  const int stride = gridDim.x * blockDim.x;
  for (int i = blockIdx.x * blockDim.x + threadIdx.x; i < total; i += stride) {
    const float4* p = (const float4*)(x + (size_t)i * 8);
    float4 a = p[0];
    float4 b = p[1];
    union { unsigned short u[8]; uint4 v; } o;
    o.u[0] = f2b(a.x); o.u[1] = f2b(a.y); o.u[2] = f2b(a.z); o.u[3] = f2b(a.w);
    o.u[4] = f2b(b.x); o.u[5] = f2b(b.y); o.u[6] = f2b(b.z); o.u[7] = f2b(b.w);
    *(uint4*)(xb + (size_t)i * 8) = o.v;
  }
}

// ---- W dequant -> bf16 [K_OUT][N_C] ----
__global__ void dequant_w_kernel(const int* __restrict__ Wq,
                                 const float* __restrict__ scales,
                                 const float* __restrict__ zeros,
                                 const float* __restrict__ mu1,
                                 const float* __restrict__ mu2,
                                 unsigned short* __restrict__ wb) {
  const int total = (K_OUT * N_C) / 8;
  const int stride = gridDim.x * blockDim.x;
  for (int i = blockIdx.x * blockDim.x + threadIdx.x; i < total; i += stride) {
    const int k  = i >> 9;
    const int nc = (i & 511) << 3;
    const int g  = nc >> 7;
    const float s = scales[k * NGRP + g];
    const float z = zeros[k * NGRP + g];
    const float f  = s * mu2[k];
    const float zf = z * f;
    const int4* q4 = (const int4*)(Wq + (size_t)k * N_C + nc);
    int4 q0 = q4[0], q1 = q4[1];
    const float4* m4 = (const float4*)(mu1 + nc);
    float4 m0 = m4[0], m1 = m4[1];
    union { unsigned short u[8]; uint4 v; } o;
    o.u[0] = f2b(((float)q0.x * f - zf) * m0.x);
    o.u[1] = f2b(((float)q0.y * f - zf) * m0.y);
    o.u[2] = f2b(((float)q0.z * f - zf) * m0.z);
    o.u[3] = f2b(((float)q0.w * f - zf) * m0.w);
    o.u[4] = f2b(((float)q1.x * f - zf) * m1.x);
    o.u[5] = f2b(((float)q1.y * f - zf) * m1.y);
    o.u[6] = f2b(((float)q1.z * f - zf) * m1.z);
    o.u[7] = f2b(((float)q1.w * f - zf) * m1.w);
    *(uint4*)(wb + (size_t)i * 8) = o.v;
  }
}

// ---- TLP bf16 GEMM: out[m][n] = sum_k Xb[m][k]*Wb[n][k] + bias[n]
// R10: restore cross-block overlap (m114 mechanism) — 2 blocks/CU.
// 128x256 tile, 8 waves (2Mx4N, per-wave 64x64), MFMA 16x16x32.
// LDS: 3 bufs x 24KB (A 8KB [128r x 64B] + B 16KB [256r x 64B]) = 72KB
//   -> 2 blocks/CU (144 <= 160KB). launch_bounds(512,4) caps regs at 128/wave
//   (est: 64 acc AGPR + 32 frag + ~14 addr) -> 16 waves/CU.
// Swizzle: R2-verified slot ^= (row>>1)&3 (0 conflicts); staging = linear LDS
// dst + inverse-swizzled global src (rule #21).
// Sync/ledger: stage(tt) = 3 gload_lds. Body t issues stage(t+2) into
// buf[(t+2)%3]. At top of body t, outstanding = stage(t+1)[3] (+ maybe
// stage(t)); vmcnt(3) proves stage(t) complete; barrier makes it CU-wide.
// Buffer safety: stage(t+2) overwrites buf[(t-1)%3]; every wave's body-(t-1)
// ds_reads were lgkm-drained before its MFMA(t-1) (data dep), which precedes
// barrier(t) in program order -> safe.
// Inter-block overlap: while block X drains its read window, block Y's waves
// feed the matrix pipe (HW wave scheduler; no compiler pipelining needed).
__global__ __launch_bounds__(512, 4) void gemm_bf16_kernel(
    const unsigned short* __restrict__ Xb,   // [M_DIM][N_C] bf16
    const unsigned short* __restrict__ Wb,   // [K_OUT][N_C] bf16
    const float* __restrict__ bias,          // [K_OUT]
    float* __restrict__ out) {               // [M_DIM][K_OUT]
  __shared__ unsigned short smem[36864];     // 72 KiB: 3 bufs x 24 KiB

  // XCD-aware bijective swizzle: 1024 blocks, 8 XCDs, 128 per XCD.
  // Consecutive swz share m-panel (A L2 reuse within XCD).
  const int bid = blockIdx.x;
  const int swz = (bid & 7) * 128 + (bid >> 3);
  const int m0 = (swz >> 4) * 128;   // 64 m-tiles
  const int n0 = (swz & 15) * 256;   // 16 n-tiles

  const int tid = threadIdx.x;
  const int w   = tid >> 6;
  const int l   = tid & 63;
  const int wr  = w >> 2;     // 0..1 -> 64 rows each
  const int wc  = w & 3;      // 0..3 -> 64 cols each

  const char* Xc = (const char*)Xb;
  const char* Wc = (const char*)Wb;
  char* ldsc = (char*)smem;

  // ---- staging voffsets (32-bit; inverse-swizzled global src) ----
  const int rS = tid >> 2;                       // 0..127
  const int sS = (tid & 3) ^ ((rS >> 1) & 3);    // slot (row+128 preserves it)
  const unsigned voffA  = (unsigned)(m0 + rS) * 8192u + (unsigned)sS * 16u;
  const unsigned voffB0 = (unsigned)(n0 + rS) * 8192u + (unsigned)sS * 16u;
  const unsigned voffB1 = (unsigned)(n0 + 128 + rS) * 8192u + (unsigned)sS * 16u;
  const int dstAu  = w * 1024;          // wave-uniform; +lane*16 implicit
  const int dstB0u = 8192 + w * 1024;
  const int dstB1u = 16384 + w * 1024;

  // ---- swizzled ds_read byte offsets (within one 24KB buffer) ----
  // A frag i: row = wr*64 + i*16 + (l&15); slot xor (row>>1)&3 is i-invariant.
  const int rdA = wr * 64 + (l & 15);
  const int offA0 = rdA * 64 + (((l >> 4) ^ ((rdA >> 1) & 3)) * 16);
  const int rdB = wc * 64 + (l & 15);
  const int offB0 = 8192 + rdB * 64 + (((l >> 4) ^ ((rdB >> 1) & 3)) * 16);

  f32x4 acc[4][4] = {};

#define STAGE(tt) { char* nb = ldsc + ((tt) % 3) * 24576;                    \
    const unsigned ko = (unsigned)(tt) * 64u;                                \
    gload_lds16(Xc + voffA + ko,  nb + dstAu);                               \
    gload_lds16(Wc + voffB0 + ko, nb + dstB0u);                              \
    gload_lds16(Wc + voffB1 + ko, nb + dstB1u); }

#define BODY(VMSTR, tt, DOSTAGE)                                             \
  { asm volatile("s_waitcnt vmcnt(" VMSTR ")\n\ts_barrier" ::: "memory");    \
    const char* bp = ldsc + ((tt) % 3) * 24576;                              \
    bf16x8 af[4], bfv[4];                                                    \
    _Pragma("unroll") for (int i = 0; i < 4; ++i)                            \
      af[i] = *(const bf16x8*)(bp + offA0 + i * 1024);                       \
    _Pragma("unroll") for (int j = 0; j < 4; ++j)                            \
      bfv[j] = *(const bf16x8*)(bp + offB0 + j * 1024);                      \
    if (DOSTAGE) STAGE((tt) + 2)                                             \
    __builtin_amdgcn_s_setprio(1);                                           \
    _Pragma("unroll") for (int i = 0; i < 4; ++i)                            \
      _Pragma("unroll") for (int j = 0; j < 4; ++j)                          \
        acc[i][j] = __builtin_amdgcn_mfma_f32_16x16x32_bf16(af[i], bfv[j],   \
                                                            acc[i][j], 0, 0, 0); \
    __builtin_amdgcn_s_setprio(0); }

  // Prologue: stage tiles 0,1 (6 loads in flight).
  STAGE(0)
  STAGE(1)

  // Main: uniform bodies t=0..125 (vmcnt(3) proves stage(t); stage t+2).
#pragma unroll 1
  for (int t = 0; t < NT - 2; ++t) BODY("3", t, 1)
  // Tail: body 126 (vmcnt(3) proves stage(126); newer = stage(127)[3]);
  //       body 127 (vmcnt(0) proves stage(127)).
  BODY("3", NT - 2, 0)
  BODY("0", NT - 1, 0)

#undef BODY
#undef STAGE

  // Epilogue: C/D layout col=lane&15, row=(lane>>4)*4+reg (verified R1/R2).
#pragma unroll
  for (int j = 0; j < 4; ++j) {
    const int col = n0 + wc * 64 + j * 16 + (l & 15);
    const float bv = bias[col];
#pragma unroll
    for (int i = 0; i < 4; ++i) {
      const int row = m0 + wr * 64 + i * 16 + (l >> 4) * 4;
#pragma unroll
      for (int rr = 0; rr < 4; ++rr)
        out[(size_t)(row + rr) * K_OUT + col] = acc[i][j][rr] + bv;
    }
  }
}

extern "C" void kernel_launch(void* const* d_in, const int* in_sizes, int n_in,
                              void* d_out, int out_size, void* d_ws, size_t ws_size,
                              hipStream_t stream) {
  const float* x      = (const float*)d_in[0];
  const int*   Wq     = (const int*)d_in[1];
  const float* scales = (const float*)d_in[2];
  const float* zeros  = (const float*)d_in[3];
  const float* mu1    = (const float*)d_in[4];
  const float* mu2    = (const float*)d_in[5];
  const float* bias   = (const float*)d_in[6];
  float* out = (float*)d_out;

  unsigned short* xb = (unsigned short*)d_ws;
  unsigned short* wb = xb + (size_t)M_DIM * N_C;

  convert_x_kernel<<<2048, 256, 0, stream>>>(x, xb);
  dequant_w_kernel<<<2048, 256, 0, stream>>>(Wq, scales, zeros, mu1, mu2, wb);

  dim3 grid((M_DIM / 128) * (K_OUT / 256));   // 1024 blocks, 2 per CU
  gemm_bf16_kernel<<<grid, 512, 0, stream>>>(xb, wb, bias, out);
}